// Round 5
// baseline (986.135 us; speedup 1.0000x reference)
//
#include <hip/hip_runtime.h>

// CapsuleTransformConv: out[b,oh,ow,n,fc] = sum_a x[b,oh+ki,ow+kj,c,a] * M[n,a,fc]
//   n = (ki*3+kj)*32 + c ; fc in [0,512)
// x[4,16,16,32,16] f32 (2MB), M[288,16,512] f32 (9.4MB), out[4,14,14,288,512] f32 (462MB)
// HBM-write-bound: floor ~76us at 6.1 TB/s (fillBuffer-verified).
//
// R2 (3rd resubmit after broker timeouts): block per (n,b,oh) = 16128 blocks
// (was 1152: latency-bound, 196-pos serial chain/wave). 256 thr x 2 fc ->
// M-slice = 32 VGPR, x loads wave-uniform (SGPR). XCD swizzle groups same-n
// blocks per XCD -> M working set 1.15MB < 4MB L2.

#define KK      3
#define CIN     32
#define IN_ATOM 16
#define FC      512            // FILTER*ATOM
#define OH      14
#define OW      14
#define BATCH   4
#define HH      16
#define WW      16
#define NN      (KK*KK*CIN)    // 288
#define NWG     (NN*BATCH*OH)  // 16128 (divisible by 8)

__global__ __launch_bounds__(256, 8)
void caps_transform_kernel(const float* __restrict__ x,
                           const float* __restrict__ m,
                           float* __restrict__ out)
{
    // XCD-aware swizzle: HW round-robins blockIdx across 8 XCDs; give each XCD
    // a contiguous logical chunk so its 36 n-values' M slices fit in its L2.
    const int orig    = blockIdx.x;
    const int logical = (orig & 7) * (NWG / 8) + (orig >> 3);

    const int n   = logical / (BATCH * OH);
    const int rem = logical % (BATCH * OH);
    const int b   = rem / OH;
    const int oh  = rem % OH;

    const int fc0 = threadIdx.x * 2;       // each thread owns 2 consecutive fc
    const int ki  = n / (KK * CIN);
    const int kj  = (n / CIN) % KK;
    const int c   = n % CIN;

    // M[n, 0..15, fc0..fc0+1] -> 32 VGPRs
    float2 mm[IN_ATOM];
    const float* mp = m + (n * IN_ATOM) * FC + fc0;
#pragma unroll
    for (int a = 0; a < IN_ATOM; ++a)
        mm[a] = *reinterpret_cast<const float2*>(mp + a * FC);

    // x row base for (b, oh+ki, kj, c): advance by ow*CIN*IN_ATOM per position.
    const float* xrow = x + (((b * HH + (oh + ki)) * WW + kj) * CIN + c) * IN_ATOM;
    // out row base for (b, oh, ow=0, n, fc0)
    float* orow = out + (((b * OH + oh) * OW) * NN + n) * FC + fc0;

#pragma unroll 2
    for (int ow = 0; ow < OW; ++ow) {
        const float* xp = xrow + ow * (CIN * IN_ATOM);
        // wave-uniform -> compiler emits s_load_dwordx16 into SGPRs
        float xv[IN_ATOM];
#pragma unroll
        for (int a = 0; a < IN_ATOM; ++a)
            xv[a] = xp[a];

        float2 acc = make_float2(0.f, 0.f);
#pragma unroll
        for (int a = 0; a < IN_ATOM; ++a) {
            acc.x += xv[a] * mm[a].x;
            acc.y += xv[a] * mm[a].y;
        }
        *reinterpret_cast<float2*>(orow + ow * (NN * FC)) = acc;
    }
}

extern "C" void kernel_launch(void* const* d_in, const int* in_sizes, int n_in,
                              void* d_out, int out_size, void* d_ws, size_t ws_size,
                              hipStream_t stream)
{
    const float* x = (const float*)d_in[0];
    const float* m = (const float*)d_in[1];
    float* out = (float*)d_out;

    caps_transform_kernel<<<dim3(NWG), dim3(256), 0, stream>>>(x, m, out);
}

// Round 7
// 763.601 us; speedup vs baseline: 1.2914x; 1.2914x over previous
//
#include <hip/hip_runtime.h>

// CapsuleTransformConv: out[b,oh,ow,n,fc] = sum_a x[b,oh+ki,ow+kj,c,a] * M[n,a,fc]
//   n = (ki*3+kj)*32 + c ; fc in [0,512)
// x[4,16,16,32,16] f32 (2MB), M[288,16,512] f32 (9.4MB), out[4,14,14,288,512] f32 (462MB)
// HBM-write-bound: floor ~76us at 6.1 TB/s (fillBuffer-verified).
//
// R6 (resubmit after broker timeout): revert R5's spatial explosion (16128
// blocks re-fetched M 516MB and scattered the write front -> 2.5GB traffic,
// 638us). Back to R1 layout (block owns (n,b), M in regs ONCE, float4 stores,
// consecutive-n blocks = contiguous write front, NO xcd swizzle), fixing R1's
// latency problem only:
//   - oh split in half -> 2304 blocks (2x waves of R1, M traffic 75MB total)
//   - launch_bounds(128,4): ~4 waves/SIMD
//   - unroll ow x2: two independent s_load->FMA->store chains in flight

#define KK      3
#define CIN     32
#define IN_ATOM 16
#define FC      512            // FILTER*ATOM
#define OH      14
#define OW      14
#define BATCH   4
#define HH      16
#define WW      16
#define NN      (KK*KK*CIN)    // 288

__global__ __launch_bounds__(128, 4)
void caps_transform_kernel(const float* __restrict__ x,
                           const float* __restrict__ m,
                           float* __restrict__ out)
{
    const int n    = blockIdx.x;           // 0..287 (consecutive blocks -> consecutive 2KB out chunks)
    const int b    = blockIdx.y;           // 0..3
    const int half = blockIdx.z;           // 0..1 (oh rows 0-6 / 7-13)
    const int fc0  = threadIdx.x * 4;      // thread owns 4 consecutive fc

    const int ki = n / (KK * CIN);
    const int kj = (n / CIN) % KK;
    const int c  = n % CIN;

    // M[n, 0..15, fc0..fc0+3] -> 64 VGPRs, loaded once per block.
    float4 mm[IN_ATOM];
    const float* mp = m + (n * IN_ATOM) * FC + fc0;
#pragma unroll
    for (int a = 0; a < IN_ATOM; ++a)
        mm[a] = *reinterpret_cast<const float4*>(mp + a * FC);

    const int oh0 = half * 7;
    const float* xb = x + ((b * HH * WW) * CIN + c) * IN_ATOM;
    float* ob = out + ((b * OH * OW) * NN + n) * FC + fc0;

    for (int r = 0; r < 7; ++r) {
        const int oh = oh0 + r;
        const float* xrow = xb + ((oh + ki) * WW + kj) * (CIN * IN_ATOM);
        float* orow = ob + oh * (OW * NN * FC);
#pragma unroll 2
        for (int ow = 0; ow < OW; ++ow) {
            const float* xp = xrow + ow * (CIN * IN_ATOM);
            // wave-uniform -> scalar s_load into SGPRs
            float xv[IN_ATOM];
#pragma unroll
            for (int a = 0; a < IN_ATOM; ++a)
                xv[a] = xp[a];

            float4 acc = make_float4(0.f, 0.f, 0.f, 0.f);
#pragma unroll
            for (int a = 0; a < IN_ATOM; ++a) {
                acc.x += xv[a] * mm[a].x;
                acc.y += xv[a] * mm[a].y;
                acc.z += xv[a] * mm[a].z;
                acc.w += xv[a] * mm[a].w;
            }
            *reinterpret_cast<float4*>(orow + ow * (NN * FC)) = acc;
        }
    }
}

extern "C" void kernel_launch(void* const* d_in, const int* in_sizes, int n_in,
                              void* d_out, int out_size, void* d_ws, size_t ws_size,
                              hipStream_t stream)
{
    const float* x = (const float*)d_in[0];
    const float* m = (const float*)d_in[1];
    float* out = (float*)d_out;

    caps_transform_kernel<<<dim3(NN, BATCH, 2), dim3(128), 0, stream>>>(x, m, out);
}

// Round 12
// 473.707 us; speedup vs baseline: 2.0817x; 1.6120x over previous
//
#include <hip/hip_runtime.h>

// CapsuleTransformConv: out[b,oh,ow,n,fc] = sum_a x[b,oh+ki,ow+kj,c,a] * M[n,a,fc]
//   n = (ki*3+kj)*32 + c ; fc in [0,512)
// x[4,16,16,32,16] f32 (2MB), M[288,16,512] f32 (9.4MB), out[4,14,14,288,512] f32 (462MB)
// HBM-write-bound: floor ~76us at 6.1 TB/s (fillBuffer-verified).
//
// R8 (resubmit; broker timeout): __builtin_nontemporal_store needs a Clang
// vector type, not HIP's struct float4 -> ext_vector_type(4). Theory: R6
// counters showed FETCH=528MB ~= out(462)+M(70) = L2 write-allocate/RFO on
// the output stream, WRITE=916MB=2x462. nt stores bypass L2 allocation ->
// no RFO fetch, single write, M stays L2-hot.

#define KK      3
#define CIN     32
#define IN_ATOM 16
#define FC      512            // FILTER*ATOM
#define OH      14
#define OW      14
#define BATCH   4
#define HH      16
#define WW      16
#define NN      (KK*KK*CIN)    // 288

typedef float f32x4 __attribute__((ext_vector_type(4)));

__global__ __launch_bounds__(128, 4)
void caps_transform_kernel(const float* __restrict__ x,
                           const float* __restrict__ m,
                           float* __restrict__ out)
{
    const int n    = blockIdx.x;           // 0..287 (consecutive blocks -> consecutive 2KB out chunks)
    const int b    = blockIdx.y;           // 0..3
    const int half = blockIdx.z;           // 0..1 (oh rows 0-6 / 7-13)
    const int fc0  = threadIdx.x * 4;      // thread owns 4 consecutive fc

    const int ki = n / (KK * CIN);
    const int kj = (n / CIN) % KK;
    const int c  = n % CIN;

    // M[n, 0..15, fc0..fc0+3] -> 64 VGPRs, loaded once per block.
    f32x4 mm[IN_ATOM];
    const float* mp = m + (n * IN_ATOM) * FC + fc0;
#pragma unroll
    for (int a = 0; a < IN_ATOM; ++a)
        mm[a] = *reinterpret_cast<const f32x4*>(mp + a * FC);

    const int oh0 = half * 7;
    const float* xb = x + ((b * HH * WW) * CIN + c) * IN_ATOM;
    float* ob = out + ((b * OH * OW) * NN + n) * FC + fc0;

    for (int r = 0; r < 7; ++r) {
        const int oh = oh0 + r;
        const float* xrow = xb + ((oh + ki) * WW + kj) * (CIN * IN_ATOM);
        float* orow = ob + oh * (OW * NN * FC);
#pragma unroll 2
        for (int ow = 0; ow < OW; ++ow) {
            const float* xp = xrow + ow * (CIN * IN_ATOM);
            // wave-uniform -> scalar s_load into SGPRs
            float xv[IN_ATOM];
#pragma unroll
            for (int a = 0; a < IN_ATOM; ++a)
                xv[a] = xp[a];

            f32x4 acc = (f32x4)(0.f);
#pragma unroll
            for (int a = 0; a < IN_ATOM; ++a)
                acc += xv[a] * mm[a];

            // non-temporal: bypass L2 allocation (no RFO, no L2 thrash)
            __builtin_nontemporal_store(acc,
                reinterpret_cast<f32x4*>(orow + ow * (NN * FC)));
        }
    }
}

extern "C" void kernel_launch(void* const* d_in, const int* in_sizes, int n_in,
                              void* d_out, int out_size, void* d_ws, size_t ws_size,
                              hipStream_t stream)
{
    const float* x = (const float*)d_in[0];
    const float* m = (const float*)d_in[1];
    float* out = (float*)d_out;

    caps_transform_kernel<<<dim3(NN, BATCH, 2), dim3(128), 0, stream>>>(x, m, out);
}

// Round 13
// 467.650 us; speedup vs baseline: 2.1087x; 1.0130x over previous
//
#include <hip/hip_runtime.h>

// CapsuleTransformConv: out[b,oh,ow,n,fc] = sum_a x[b,oh+ki,ow+kj,c,a] * M[n,a,fc]
//   n = (ki*3+kj)*32 + c ; fc in [0,512)
// x[4,16,16,32,16] f32 (2MB), M[288,16,512] f32 (9.4MB), out[4,14,14,288,512] f32 (462MB)
// HBM-write-bound: floor ~76us at 6.1-6.3 TB/s (fillBuffer-verified).
//
// R13: R12 (nt stores, kernel ~110us) + ONE change: oh split 2 -> 7
// (2 rows/block) => 8064 blocks / 16128 waves (63 waves/CU, saturated).
// M re-read is L2-safe now: 288 % 8 == 0 so linear-block XCD round-robin
// pins n===r (mod 8) to XCD r -> per-XCD M working set = 36*32KB = 1.15MB
// < 4MB L2, and nt stores no longer thrash L2 (R12's fix). R5's failure
// mode (M evicted by write-allocate stream) is structurally gone.

#define KK      3
#define CIN     32
#define IN_ATOM 16
#define FC      512            // FILTER*ATOM
#define OH      14
#define OW      14
#define BATCH   4
#define HH      16
#define WW      16
#define NN      (KK*KK*CIN)    // 288

typedef float f32x4 __attribute__((ext_vector_type(4)));

__global__ __launch_bounds__(128, 4)
void caps_transform_kernel(const float* __restrict__ x,
                           const float* __restrict__ m,
                           float* __restrict__ out)
{
    const int n    = blockIdx.x;           // 0..287 (fastest -> XCD = n%8, M slices L2-pinned)
    const int b    = blockIdx.y;           // 0..3
    const int seg  = blockIdx.z;           // 0..6 (oh pair)
    const int fc0  = threadIdx.x * 4;      // thread owns 4 consecutive fc

    const int ki = n / (KK * CIN);
    const int kj = (n / CIN) % KK;
    const int c  = n % CIN;

    // M[n, 0..15, fc0..fc0+3] -> 64 VGPRs, loaded once per block (L2-hot).
    f32x4 mm[IN_ATOM];
    const float* mp = m + (n * IN_ATOM) * FC + fc0;
#pragma unroll
    for (int a = 0; a < IN_ATOM; ++a)
        mm[a] = *reinterpret_cast<const f32x4*>(mp + a * FC);

    const int oh0 = seg * 2;
    const float* xb = x + ((b * HH * WW) * CIN + c) * IN_ATOM;
    float* ob = out + ((b * OH * OW) * NN + n) * FC + fc0;

#pragma unroll
    for (int r = 0; r < 2; ++r) {
        const int oh = oh0 + r;
        const float* xrow = xb + ((oh + ki) * WW + kj) * (CIN * IN_ATOM);
        float* orow = ob + oh * (OW * NN * FC);
#pragma unroll 2
        for (int ow = 0; ow < OW; ++ow) {
            const float* xp = xrow + ow * (CIN * IN_ATOM);
            // wave-uniform -> scalar s_load into SGPRs
            float xv[IN_ATOM];
#pragma unroll
            for (int a = 0; a < IN_ATOM; ++a)
                xv[a] = xp[a];

            f32x4 acc = (f32x4)(0.f);
#pragma unroll
            for (int a = 0; a < IN_ATOM; ++a)
                acc += xv[a] * mm[a];

            // non-temporal: bypass L2 allocation (no RFO, no L2 thrash)
            __builtin_nontemporal_store(acc,
                reinterpret_cast<f32x4*>(orow + ow * (NN * FC)));
        }
    }
}

extern "C" void kernel_launch(void* const* d_in, const int* in_sizes, int n_in,
                              void* d_out, int out_size, void* d_ws, size_t ws_size,
                              hipStream_t stream)
{
    const float* x = (const float*)d_in[0];
    const float* m = (const float*)d_in[1];
    float* out = (float*)d_out;

    caps_transform_kernel<<<dim3(NN, BATCH, 7), dim3(128), 0, stream>>>(x, m, out);
}